// Round 13
// baseline (132.445 us; speedup 1.0000x reference)
//
#include <hip/hip_runtime.h>
#include <math.h>

#define B_ 16
#define L_ 256
#define D_ 64

#define CHUNK 8                     // 512 blocks = 2 blocks/CU (LDS 63.5KB x2 fits 160KB)
#define WARM  5                     // level-k row exact at tw+k; row 62 = level 5 -> exact at T0
#define NCH   (L_ / CHUNK)          // 32 chunks

#define PITCH 64                    // 16 quads/slot; phys quad = dq ^ v; edge floats via
                                    // scalar LDS reads (R12-proven; DPP edges failed R11)
#define NSLOT 127                   // slot 0 = zeros (concat row -1); 1..64 = x rows 0..63;
                                    // 65..126 = h(t-1) rows 0..61
#define FBUF  (NSLOT * PITCH)       // 8128 floats
#define LDSZ  (2 * FBUF)            // 16256 floats = 63.5 KB

// fast tanh via v_exp_f32: overflow/NaN-safe, ~1e-7 rel error (thr 1e-2)
__device__ __forceinline__ float ftanh(float x) {
    float ax = fabsf(x);
    float e  = __builtin_amdgcn_exp2f(-2.8853900818f * ax);   // e^{-2ax}
    float r  = (1.0f - e) * __builtin_amdgcn_rcpf(1.0f + e);
    return copysignf(r, x);
}

// DPP wave shifts with zero boundary fill (bound_ctrl=1) — used ONLY in scan63
// (single fully-active wave; validated there since R3).
__device__ __forceinline__ float dpp_shr1(float x) {
    int r = __builtin_amdgcn_update_dpp(0, __float_as_int(x), 0x138, 0xF, 0xF, true);
    return __int_as_float(r);
}
__device__ __forceinline__ float dpp_shl1(float x) {
    int r = __builtin_amdgcn_update_dpp(0, __float_as_int(x), 0x130, 0xF, 0xF, true);
    return __int_as_float(r);
}

// ---------------------------------------------------------------------------
// fused_layer: rows 0..62 for a (b, t-chunk of 8), serial over t. Full x(t)
// frame + h(t-1) rows 0..61 in one double-buffered XOR-swizzled LDS frame.
// Per tap slot a lane reads its own 2 quads (2x ds_read_b128) + 2 edge floats
// as scalar LDS reads (masked at l8==0/7 where the column zero-pad applies).
// Slot s holds concat row s-1; data quad dq of slot s at phys quad dq^((s>>1)&7).
// WARM=5: level-k rows exact at tw+k (k<=5), so all rows exact from T0.
// Row 63 (truly recurrent) is finished by scan63.
__global__ __launch_bounds__(512, 1) void fused_layer(
        const float* __restrict__ X, float* __restrict__ H,
        const float* __restrict__ Wl, const float* __restrict__ bl) {
    __shared__ float lds[LDSZ];

    const int tid    = threadIdx.x;
    const int b      = blockIdx.x >> 5;                // 32 chunks per batch
    const int ch     = blockIdx.x & (NCH - 1);
    const int T0     = ch * CHUNK;
    const int tw     = (T0 >= WARM) ? (T0 - WARM) : 0;
    const int tend   = T0 + CHUNK;
    const int btbase = b * L_;

    const int r   = tid >> 3;                          // row 0..63
    const int l8  = tid & 7;
    const int q0  = l8 << 1;                           // own data quads q0, q0+1
    // x-staging offsets (all 512 threads)
    const int sx  = r + 1;
    const int vx  = (sx >> 1) & 7;
    const int xw0 = sx * PITCH + ((q0 ^ vx) << 2);
    const int xw1 = sx * PITCH + (((q0 + 1) ^ vx) << 2);
    // compute mapping: threads 0..503 -> output rows 0..62
    const bool comp = tid < 504;
    const int  i    = r;
    const int  c0   = l8 << 3;
    const int  sh   = 65 + i;                          // h-store slot (i<=61)
    const int  vh   = (sh >> 1) & 7;
    const int  hw0  = sh * PITCH + ((q0 ^ vh) << 2);
    const int  hw1  = sh * PITCH + (((q0 + 1) ^ vh) << 2);
    const bool le0  = (l8 == 0);
    const bool le7  = (l8 == 7);
    const int  qm   = le0 ? q0 : (q0 - 1);             // clamped; value masked
    const int  qp   = le7 ? q0 : (q0 + 2);

    // per-ki read offsets (slots 2i..2i+2), precomputed once
    int ro0[3], ro1[3], rle[3], rre[3];
#pragma unroll
    for (int ki = 0; ki < 3; ++ki) {
        const int s = 2 * i + ki;
        const int v = (s >> 1) & 7;
        const int sb = s * PITCH;
        ro0[ki] = sb + ((q0 ^ v) << 2);
        ro1[ki] = sb + (((q0 + 1) ^ v) << 2);
        rle[ki] = sb + ((qm ^ v) << 2) + 3;            // data col c0-1 (pos 3 of quad q0-1)
        rre[ki] = sb + ((qp ^ v) << 2);                // data col c0+8 (pos 0 of quad q0+2)
    }

    float w[9];
#pragma unroll
    for (int k = 0; k < 9; ++k) w[k] = Wl[k];
    const float bias = bl[0];
    const float4 z4 = make_float4(0.f, 0.f, 0.f, 0.f);

    // zero both frames (slot 0 + h(-1)=0; warm-up fixes the rest)
    for (int k = tid; k < LDSZ / 4; k += 512)
        reinterpret_cast<float4*>(lds)[k] = z4;
    __syncthreads();

    float* cur = lds;
    float* nxt = lds + FBUF;

    // stage x(tw) into cur ((r<<6)+(l8<<3) == tid<<3)
    {
        const float* xg = X + (((size_t)(btbase + tw)) << 12) + (tid << 3);
        *reinterpret_cast<float4*>(cur + xw0) = reinterpret_cast<const float4*>(xg)[0];
        *reinterpret_cast<float4*>(cur + xw1) = reinterpret_cast<const float4*>(xg)[1];
    }
    // register prefetch x(tw+1)
    float4 pa, pb;
    {
        const int t1 = (tw + 1 < L_) ? tw + 1 : L_ - 1;
        const float* xg = X + (((size_t)(btbase + t1)) << 12) + (tid << 3);
        pa = reinterpret_cast<const float4*>(xg)[0];
        pb = reinterpret_cast<const float4*>(xg)[1];
    }
    __syncthreads();

    for (int t = tw; t < tend; ++t) {
        // issue x(t+2) loads — 2 steps deep, off the serial chain
        const int t2 = (t + 2 < L_) ? t + 2 : L_ - 1;
        const float* xg = X + (((size_t)(btbase + t2)) << 12) + (tid << 3);
        const float4 na = reinterpret_cast<const float4*>(xg)[0];
        const float4 nb = reinterpret_cast<const float4*>(xg)[1];

        if (comp) {
            float acc[8];
#pragma unroll
            for (int k = 0; k < 8; ++k) acc[k] = bias;
#pragma unroll
            for (int ki = 0; ki < 3; ++ki) {
                const float4 o0 = *reinterpret_cast<const float4*>(cur + ro0[ki]);
                const float4 o1 = *reinterpret_cast<const float4*>(cur + ro1[ki]);
                const float eLv = cur[rle[ki]];
                const float eRv = cur[rre[ki]];
                // e[0..9] = cols c0-1 .. c0+8 of concat row 2i-1+ki
                float e[10];
                e[0] = le0 ? 0.f : eLv;
                e[1] = o0.x; e[2] = o0.y; e[3] = o0.z; e[4] = o0.w;
                e[5] = o1.x; e[6] = o1.y; e[7] = o1.z; e[8] = o1.w;
                e[9] = le7 ? 0.f : eRv;
                const float wa = w[ki*3], wb = w[ki*3+1], wc = w[ki*3+2];
#pragma unroll
                for (int k = 0; k < 8; ++k)
                    acc[k] = fmaf(wa, e[k], fmaf(wb, e[k+1], fmaf(wc, e[k+2], acc[k])));
            }
            float o[8];
#pragma unroll
            for (int k = 0; k < 8; ++k) o[k] = ftanh(acc[k]);

            if (t >= T0) {                             // skip warm-up writes
                float* gd = H + (((size_t)(btbase + t)) << 12) + (i << 6) + c0;
                *reinterpret_cast<float4*>(gd)     = make_float4(o[0],o[1],o[2],o[3]);
                *reinterpret_cast<float4*>(gd + 4) = make_float4(o[4],o[5],o[6],o[7]);
            }
            if (i <= 61) {                             // h row for next step
                *reinterpret_cast<float4*>(nxt + hw0) = make_float4(o[0],o[1],o[2],o[3]);
                *reinterpret_cast<float4*>(nxt + hw1) = make_float4(o[4],o[5],o[6],o[7]);
            }
        }
        {   // commit x(t+1) into nxt
            *reinterpret_cast<float4*>(nxt + xw0) = pa;
            *reinterpret_cast<float4*>(nxt + xw1) = pb;
        }
        __syncthreads();
        pa = na; pb = nb;
        float* tmp = cur; cur = nxt; nxt = tmp;
    }
}

// ---------------------------------------------------------------------------
// Sequential scan for row 63 (reads rows 61/62 from global, written above).
#define SDEPTH 16
__global__ void scan63(float* __restrict__ dst,
                       const float* __restrict__ src,
                       const float* __restrict__ Wl,
                       const float* __restrict__ bl) {
    const int b = blockIdx.x;
    const int j = threadIdx.x;                         // 0..63, one wave
    float w[9];
#pragma unroll
    for (int k = 0; k < 9; ++k) w[k] = Wl[k];
    const float bias = bl[0];

    const size_t ST = (size_t)D_ * D_;
    const float* s61 = src + (size_t)b * L_ * ST + 61 * 64 + j;
    const float* s62 = src + (size_t)b * L_ * ST + 62 * 64 + j;
    float*       d63 = dst + (size_t)b * L_ * ST + 63 * 64 + j;

    float s = ftanh(bias);                             // t=0: h_{-1}=0
    d63[0] = s;

    float p61[SDEPTH], p62[SDEPTH];
#pragma unroll
    for (int u = 0; u < SDEPTH; ++u) {
        p61[u] = s61[(size_t)u * ST];
        p62[u] = s62[(size_t)u * ST];
    }

    for (int t0 = 1; t0 < 256; t0 += SDEPTH) {
#pragma unroll
        for (int u = 0; u < SDEPTH; ++u) {
            const int t = t0 + u;
            if (t > 255) break;
            const float r61 = p61[u], r62 = p62[u];
            int tp = t + SDEPTH - 1;
            if (tp > 255) tp = 255;
            p61[u] = s61[(size_t)tp * ST];
            p62[u] = s62[(size_t)tp * ST];
            float l1 = dpp_shr1(r61), q1 = dpp_shl1(r61);
            float l2 = dpp_shr1(r62), q2 = dpp_shl1(r62);
            float p = bias;
            p = fmaf(w[0], l1, p); p = fmaf(w[1], r61, p); p = fmaf(w[2], q1, p);
            p = fmaf(w[3], l2, p); p = fmaf(w[4], r62, p); p = fmaf(w[5], q2, p);
            float ls = dpp_shr1(s), rs = dpp_shl1(s);
            float z = fmaf(w[6], ls, fmaf(w[7], s, fmaf(w[8], rs, p)));
            s = ftanh(z);
            d63[(size_t)t * ST] = s;
        }
    }
}

extern "C" void kernel_launch(void* const* d_in, const int* in_sizes, int n_in,
                              void* d_out, int out_size, void* d_ws, size_t ws_size,
                              hipStream_t stream) {
    const float* x    = (const float*)d_in[0];   // (B,L,D,D)
    const float* W    = (const float*)d_in[1];   // (2,1,1,3,3)
    const float* bias = (const float*)d_in[2];   // (2,)
    float* out = (float*)d_out;
    float* h1  = (float*)d_ws;

    for (int l = 0; l < 2; ++l) {
        const float* X  = (l == 0) ? x  : h1;
        float*       H  = (l == 0) ? h1 : out;
        fused_layer<<<B_ * NCH, 512, 0, stream>>>(X, H, W + l * 9, bias + l);
        scan63<<<B_, 64, 0, stream>>>(H, H, W + l * 9, bias + l);
    }
}

// Round 14
// 130.042 us; speedup vs baseline: 1.0185x; 1.0185x over previous
//
#include <hip/hip_runtime.h>
#include <math.h>

#define B_ 16
#define L_ 256
#define D_ 64

#define CHUNK 16                    // 256 blocks = 1/CU (R13: 2/CU doesn't help — shared LDS pipe)
#define WARM  5                     // R13-proven
#define NCH   (L_ / CHUNK)

#define PITCH 64                    // 16 quads/slot; phys quad = dq ^ v
#define NSLOT 127                   // slot 0 = zeros; 1..64 = x rows 0..63; 65..126 = h rows 0..61
#define FBUF  (NSLOT * PITCH)       // 8128 floats
#define LDSZ  (2 * FBUF)            // 63.5 KB

// fast tanh via v_exp_f32: overflow/NaN-safe, ~1e-7 rel error (thr 1e-2)
__device__ __forceinline__ float ftanh(float x) {
    float ax = fabsf(x);
    float e  = __builtin_amdgcn_exp2f(-2.8853900818f * ax);   // e^{-2ax}
    float r  = (1.0f - e) * __builtin_amdgcn_rcpf(1.0f + e);
    return copysignf(r, x);
}

// DPP wave shifts (zero fill) — used ONLY in scan63 (full-wave, proven since R3)
__device__ __forceinline__ float dpp_shr1(float x) {
    int r = __builtin_amdgcn_update_dpp(0, __float_as_int(x), 0x138, 0xF, 0xF, true);
    return __int_as_float(r);
}
__device__ __forceinline__ float dpp_shl1(float x) {
    int r = __builtin_amdgcn_update_dpp(0, __float_as_int(x), 0x130, 0xF, 0xF, true);
    return __int_as_float(r);
}

// async global->LDS, 16B per lane; dest = wave-uniform base + lane*16 (linear)
__device__ __forceinline__ void gl_lds16(const float* g, float* l) {
    __builtin_amdgcn_global_load_lds(
        (const __attribute__((address_space(1))) void*)g,
        (__attribute__((address_space(3))) void*)l, 16, 0, 0);
}

// ---------------------------------------------------------------------------
// fused_layer: rows 0..62 per (b, t-chunk of 16), serial over t. x(t) staged
// via global_load_lds with PRE-SWIZZLED per-lane SOURCE addresses (linear LDS
// dest, m173 pattern; XOR is its own inverse): phys quad p of slot s receives
// data quad p^v(s), so swizzled reads recover data quad q at phys q^v.
// h(t-1) rows 0..61 in the same double-buffered frame (reg->LDS swizzled
// writes). Per tap slot: 2x ds_read_b128 (own cols) + 2 scalar edge reads
// (masked at l8==0/7). WARM=5 warm-up makes chunk starts exact (level-k row
// exact at tw+k, k<=5). Row 63 finished by scan63.
__global__ __launch_bounds__(512, 1) void fused_layer(
        const float* __restrict__ X, float* __restrict__ H,
        const float* __restrict__ Wl, const float* __restrict__ bl) {
    __shared__ float lds[LDSZ];

    const int tid    = threadIdx.x;
    const int b      = blockIdx.x >> 4;
    const int ch     = blockIdx.x & (NCH - 1);
    const int T0     = ch * CHUNK;
    const int tw     = (T0 >= WARM) ? (T0 - WARM) : 0;
    const int tend   = T0 + CHUNK;
    const int btbase = b * L_;

    const int r   = tid >> 3;                          // compute row 0..63
    const int l8  = tid & 7;
    const int q0  = l8 << 1;
    // async x-staging geometry: wave wv stages slots 8wv+1..8wv+8 (2 instrs)
    const int lane  = tid & 63;
    const int wv    = tid >> 6;
    const int row0  = (wv << 3) + (lane >> 4);         // instr-0 source row
    const int row1  = row0 + 4;                        // instr-1 source row
    const int dq0   = (lane & 15) ^ (((row0 + 1) >> 1) & 7);
    const int dq1   = (lane & 15) ^ (((row1 + 1) >> 1) & 7);
    const int soff0 = (row0 << 6) + (dq0 << 2);        // per-lane global offs
    const int soff1 = (row1 << 6) + (dq1 << 2);
    const int doff0 = ((wv << 3) + 1) << 6;            // wave-uniform LDS offs
    const int doff1 = ((wv << 3) + 5) << 6;
    // compute mapping: threads 0..503 -> output rows 0..62
    const bool comp = tid < 504;
    const int  i    = r;
    const int  c0   = l8 << 3;
    const int  sh   = 65 + i;                          // h-store slot (i<=61)
    const int  vh   = (sh >> 1) & 7;
    const int  hw0  = sh * PITCH + ((q0 ^ vh) << 2);
    const int  hw1  = sh * PITCH + (((q0 + 1) ^ vh) << 2);
    const bool le0  = (l8 == 0);
    const bool le7  = (l8 == 7);
    const int  qm   = le0 ? q0 : (q0 - 1);             // clamped; value masked
    const int  qp   = le7 ? q0 : (q0 + 2);

    int ro0[3], ro1[3], rle[3], rre[3];
#pragma unroll
    for (int ki = 0; ki < 3; ++ki) {
        const int s = 2 * i + ki;
        const int v = (s >> 1) & 7;
        const int sb = s * PITCH;
        ro0[ki] = sb + ((q0 ^ v) << 2);
        ro1[ki] = sb + (((q0 + 1) ^ v) << 2);
        rle[ki] = sb + ((qm ^ v) << 2) + 3;            // col c0-1
        rre[ki] = sb + ((qp ^ v) << 2);                // col c0+8
    }

    float w[9];
#pragma unroll
    for (int k = 0; k < 9; ++k) w[k] = Wl[k];
    const float bias = bl[0];
    const float4 z4 = make_float4(0.f, 0.f, 0.f, 0.f);

    for (int k = tid; k < LDSZ / 4; k += 512)
        reinterpret_cast<float4*>(lds)[k] = z4;        // slot 0 + h(-1)=0
    __syncthreads();

    float* cur = lds;
    float* nxt = lds + FBUF;

    {   // stage x(tw) into cur (async; drained by the barrier below)
        const float* xf = X + ((size_t)(btbase + tw) << 12);
        gl_lds16(xf + soff0, cur + doff0);
        gl_lds16(xf + soff1, cur + doff1);
    }
    __syncthreads();

    for (int t = tw; t < tend; ++t) {
        {   // issue async x(t+1) copy into nxt — consumed after the barrier
            const int tn = (t + 1 < L_) ? t + 1 : L_ - 1;
            const float* xf = X + ((size_t)(btbase + tn) << 12);
            gl_lds16(xf + soff0, nxt + doff0);
            gl_lds16(xf + soff1, nxt + doff1);
        }

        if (comp) {
            float acc[8];
#pragma unroll
            for (int k = 0; k < 8; ++k) acc[k] = bias;
#pragma unroll
            for (int ki = 0; ki < 3; ++ki) {
                const float4 o0 = *reinterpret_cast<const float4*>(cur + ro0[ki]);
                const float4 o1 = *reinterpret_cast<const float4*>(cur + ro1[ki]);
                const float eLv = cur[rle[ki]];
                const float eRv = cur[rre[ki]];
                float e[10];
                e[0] = le0 ? 0.f : eLv;
                e[1] = o0.x; e[2] = o0.y; e[3] = o0.z; e[4] = o0.w;
                e[5] = o1.x; e[6] = o1.y; e[7] = o1.z; e[8] = o1.w;
                e[9] = le7 ? 0.f : eRv;
                const float wa = w[ki*3], wb = w[ki*3+1], wc = w[ki*3+2];
#pragma unroll
                for (int k = 0; k < 8; ++k)
                    acc[k] = fmaf(wa, e[k], fmaf(wb, e[k+1], fmaf(wc, e[k+2], acc[k])));
            }
            float o[8];
#pragma unroll
            for (int k = 0; k < 8; ++k) o[k] = ftanh(acc[k]);

            if (t >= T0) {
                float* gd = H + (((size_t)(btbase + t)) << 12) + (i << 6) + c0;
                *reinterpret_cast<float4*>(gd)     = make_float4(o[0],o[1],o[2],o[3]);
                *reinterpret_cast<float4*>(gd + 4) = make_float4(o[4],o[5],o[6],o[7]);
            }
            if (i <= 61) {
                *reinterpret_cast<float4*>(nxt + hw0) = make_float4(o[0],o[1],o[2],o[3]);
                *reinterpret_cast<float4*>(nxt + hw1) = make_float4(o[4],o[5],o[6],o[7]);
            }
        }
        __syncthreads();                               // drains lgkm + vmcnt
        float* tmp = cur; cur = nxt; nxt = tmp;
    }
}

// ---------------------------------------------------------------------------
// Sequential scan for row 63 (reads rows 61/62 from global, written above).
#define SDEPTH 16
__global__ void scan63(float* __restrict__ dst,
                       const float* __restrict__ src,
                       const float* __restrict__ Wl,
                       const float* __restrict__ bl) {
    const int b = blockIdx.x;
    const int j = threadIdx.x;                         // 0..63, one wave
    float w[9];
#pragma unroll
    for (int k = 0; k < 9; ++k) w[k] = Wl[k];
    const float bias = bl[0];

    const size_t ST = (size_t)D_ * D_;
    const float* s61 = src + (size_t)b * L_ * ST + 61 * 64 + j;
    const float* s62 = src + (size_t)b * L_ * ST + 62 * 64 + j;
    float*       d63 = dst + (size_t)b * L_ * ST + 63 * 64 + j;

    float s = ftanh(bias);                             // t=0: h_{-1}=0
    d63[0] = s;

    float p61[SDEPTH], p62[SDEPTH];
#pragma unroll
    for (int u = 0; u < SDEPTH; ++u) {
        p61[u] = s61[(size_t)u * ST];
        p62[u] = s62[(size_t)u * ST];
    }

    for (int t0 = 1; t0 < 256; t0 += SDEPTH) {
#pragma unroll
        for (int u = 0; u < SDEPTH; ++u) {
            const int t = t0 + u;
            if (t > 255) break;
            const float r61 = p61[u], r62 = p62[u];
            int tp = t + SDEPTH - 1;
            if (tp > 255) tp = 255;
            p61[u] = s61[(size_t)tp * ST];
            p62[u] = s62[(size_t)tp * ST];
            float l1 = dpp_shr1(r61), q1 = dpp_shl1(r61);
            float l2 = dpp_shr1(r62), q2 = dpp_shl1(r62);
            float p = bias;
            p = fmaf(w[0], l1, p); p = fmaf(w[1], r61, p); p = fmaf(w[2], q1, p);
            p = fmaf(w[3], l2, p); p = fmaf(w[4], r62, p); p = fmaf(w[5], q2, p);
            float ls = dpp_shr1(s), rs = dpp_shl1(s);
            float z = fmaf(w[6], ls, fmaf(w[7], s, fmaf(w[8], rs, p)));
            s = ftanh(z);
            d63[(size_t)t * ST] = s;
        }
    }
}

extern "C" void kernel_launch(void* const* d_in, const int* in_sizes, int n_in,
                              void* d_out, int out_size, void* d_ws, size_t ws_size,
                              hipStream_t stream) {
    const float* x    = (const float*)d_in[0];   // (B,L,D,D)
    const float* W    = (const float*)d_in[1];   // (2,1,1,3,3)
    const float* bias = (const float*)d_in[2];   // (2,)
    float* out = (float*)d_out;
    float* h1  = (float*)d_ws;

    for (int l = 0; l < 2; ++l) {
        const float* X  = (l == 0) ? x  : h1;
        float*       H  = (l == 0) ? h1 : out;
        fused_layer<<<B_ * NCH, 512, 0, stream>>>(X, H, W + l * 9, bias + l);
        scan63<<<B_, 64, 0, stream>>>(H, H, W + l * 9, bias + l);
    }
}

// Round 15
// 119.581 us; speedup vs baseline: 1.1076x; 1.0875x over previous
//
#include <hip/hip_runtime.h>
#include <math.h>

#define B_ 16
#define L_ 256
#define D_ 64

#define CHUNK 16                    // 256 blocks = 1/CU
#define WARM  5                     // R13-proven
#define NCH   (L_ / CHUNK)

#define PITCH 64                    // 16 quads/slot; phys quad = dq ^ v
#define NSLOT 127                   // slot 0 = zeros; 1..64 = x rows 0..63; 65..126 = h rows 0..61
#define FBUF  (NSLOT * PITCH)       // 8128 floats
#define LDSZ  (2 * FBUF)            // 63.5 KB

// fast tanh via v_exp_f32: overflow/NaN-safe, ~1e-7 rel error (thr 1e-2)
__device__ __forceinline__ float ftanh(float x) {
    float ax = fabsf(x);
    float e  = __builtin_amdgcn_exp2f(-2.8853900818f * ax);   // e^{-2ax}
    float r  = (1.0f - e) * __builtin_amdgcn_rcpf(1.0f + e);
    return copysignf(r, x);
}

// DPP wave shifts with zero boundary fill (bound_ctrl=1).
// R11 lesson: ONLY safe when executed with a fully-uniform exec mask —
// here they run in the non-divergent compute region (and in scan63's
// single fully-active wave).
__device__ __forceinline__ float dpp_shr1(float x) {
    int r = __builtin_amdgcn_update_dpp(0, __float_as_int(x), 0x138, 0xF, 0xF, true);
    return __int_as_float(r);
}
__device__ __forceinline__ float dpp_shl1(float x) {
    int r = __builtin_amdgcn_update_dpp(0, __float_as_int(x), 0x130, 0xF, 0xF, true);
    return __int_as_float(r);
}

// ---------------------------------------------------------------------------
// fused_layer: rows 0..62 per (b, t-chunk of 16), serial over t. x(t) frame +
// h(t-1) rows 0..61 in one double-buffered XOR-swizzled LDS frame (slot s =
// concat row s-1; data quad dq at phys quad dq^((s>>1)&7)). Staging = R12's
// proven 2-deep register prefetch + swizzled ds_write (R14's global_load_lds
// regressed). Column conv is decomposed as u0/u1/u2 partial sums so the two
// cross-column edge terms come from neighbor lanes via DPP (u0[7] left,
// u2[0] right) — removes the 6 scalar edge LDS reads per thread-step that
// R12-R14 counters indict as the bank-conflict source. Compute is executed
// by ALL 512 threads (row-63 lanes use clamped offsets, results discarded)
// so the DPP ops see a uniform exec mask; stores are predicated afterwards.
// WARM=5: level-k rows exact at tw+k (k<=5). Row 63 finished by scan63.
__global__ __launch_bounds__(512, 1) void fused_layer(
        const float* __restrict__ X, float* __restrict__ H,
        const float* __restrict__ Wl, const float* __restrict__ bl) {
    __shared__ float lds[LDSZ];

    const int tid    = threadIdx.x;
    const int b      = blockIdx.x >> 4;
    const int ch     = blockIdx.x & (NCH - 1);
    const int T0     = ch * CHUNK;
    const int tw     = (T0 >= WARM) ? (T0 - WARM) : 0;
    const int tend   = T0 + CHUNK;
    const int btbase = b * L_;

    const int r   = tid >> 3;                          // row 0..63
    const int l8  = tid & 7;
    const int q0  = l8 << 1;                           // own data quads q0, q0+1
    // x-staging offsets (all 512 threads)
    const int sx  = r + 1;
    const int vx  = (sx >> 1) & 7;
    const int xw0 = sx * PITCH + ((q0 ^ vx) << 2);
    const int xw1 = sx * PITCH + (((q0 + 1) ^ vx) << 2);
    // compute mapping: row i; row-63 lanes compute row 62's values (discarded)
    const int  i    = r;
    const int  ic   = (i < 63) ? i : 62;               // clamped read row
    const int  c0   = l8 << 3;
    const int  sh   = 65 + i;                          // h-store slot (i<=61)
    const int  vh   = (sh >> 1) & 7;
    const int  hw0  = sh * PITCH + ((q0 ^ vh) << 2);
    const int  hw1  = sh * PITCH + (((q0 + 1) ^ vh) << 2);
    const bool le0  = (l8 == 0);
    const bool le7  = (l8 == 7);

    // per-ki read offsets (slots 2ic..2ic+2)
    int ro0[3], ro1[3];
#pragma unroll
    for (int ki = 0; ki < 3; ++ki) {
        const int s = 2 * ic + ki;
        const int v = (s >> 1) & 7;
        const int sb = s * PITCH;
        ro0[ki] = sb + ((q0 ^ v) << 2);
        ro1[ki] = sb + (((q0 + 1) ^ v) << 2);
    }

    float w[9];
#pragma unroll
    for (int k = 0; k < 9; ++k) w[k] = Wl[k];
    const float bias = bl[0];
    const float4 z4 = make_float4(0.f, 0.f, 0.f, 0.f);

    for (int k = tid; k < LDSZ / 4; k += 512)
        reinterpret_cast<float4*>(lds)[k] = z4;        // slot 0 + h(-1)=0
    __syncthreads();

    float* cur = lds;
    float* nxt = lds + FBUF;

    // stage x(tw) into cur ((r<<6)+(l8<<3) == tid<<3)
    {
        const float* xg = X + (((size_t)(btbase + tw)) << 12) + (tid << 3);
        *reinterpret_cast<float4*>(cur + xw0) = reinterpret_cast<const float4*>(xg)[0];
        *reinterpret_cast<float4*>(cur + xw1) = reinterpret_cast<const float4*>(xg)[1];
    }
    // register prefetch x(tw+1)
    float4 pa, pb;
    {
        const int t1 = (tw + 1 < L_) ? tw + 1 : L_ - 1;
        const float* xg = X + (((size_t)(btbase + t1)) << 12) + (tid << 3);
        pa = reinterpret_cast<const float4*>(xg)[0];
        pb = reinterpret_cast<const float4*>(xg)[1];
    }
    __syncthreads();

    for (int t = tw; t < tend; ++t) {
        // issue x(t+2) loads — 2 steps deep, off the serial chain
        const int t2 = (t + 2 < L_) ? t + 2 : L_ - 1;
        const float* xg = X + (((size_t)(btbase + t2)) << 12) + (tid << 3);
        const float4 na = reinterpret_cast<const float4*>(xg)[0];
        const float4 nb = reinterpret_cast<const float4*>(xg)[1];

        // ---- non-divergent compute (all 512 threads) ----
        float u0[8], u1[8], u2[8];
#pragma unroll
        for (int k = 0; k < 8; ++k) { u0[k] = 0.f; u1[k] = bias; u2[k] = 0.f; }
#pragma unroll
        for (int ki = 0; ki < 3; ++ki) {
            const float4 o0 = *reinterpret_cast<const float4*>(cur + ro0[ki]);
            const float4 o1 = *reinterpret_cast<const float4*>(cur + ro1[ki]);
            const float g[8] = {o0.x, o0.y, o0.z, o0.w, o1.x, o1.y, o1.z, o1.w};
            const float wa = w[ki*3], wb = w[ki*3+1], wc = w[ki*3+2];
#pragma unroll
            for (int k = 0; k < 8; ++k) {
                u0[k] = fmaf(wa, g[k], u0[k]);
                u1[k] = fmaf(wb, g[k], u1[k]);
                u2[k] = fmaf(wc, g[k], u2[k]);
            }
        }
        // cross-lane edges (uniform exec): left lane's u0[7], right lane's u2[0]
        const float eLr = dpp_shr1(u0[7]);
        const float eRr = dpp_shl1(u2[0]);
        const float eL  = le0 ? 0.f : eLr;             // col c0-1 term (w-left)
        const float eR  = le7 ? 0.f : eRr;             // col c0+8 term (w-right)

        float o[8];
        o[0] = ftanh(eL + u1[0] + u2[1]);
#pragma unroll
        for (int k = 1; k < 7; ++k)
            o[k] = ftanh(u0[k-1] + u1[k] + u2[k+1]);
        o[7] = ftanh(u0[6] + u1[7] + eR);

        // ---- predicated stores (divergence after all DPP) ----
        if (i < 63 && t >= T0) {
            float* gd = H + (((size_t)(btbase + t)) << 12) + (i << 6) + c0;
            *reinterpret_cast<float4*>(gd)     = make_float4(o[0],o[1],o[2],o[3]);
            *reinterpret_cast<float4*>(gd + 4) = make_float4(o[4],o[5],o[6],o[7]);
        }
        if (i <= 61) {                                 // h row for next step
            *reinterpret_cast<float4*>(nxt + hw0) = make_float4(o[0],o[1],o[2],o[3]);
            *reinterpret_cast<float4*>(nxt + hw1) = make_float4(o[4],o[5],o[6],o[7]);
        }
        {   // commit x(t+1) into nxt
            *reinterpret_cast<float4*>(nxt + xw0) = pa;
            *reinterpret_cast<float4*>(nxt + xw1) = pb;
        }
        __syncthreads();
        pa = na; pb = nb;
        float* tmp = cur; cur = nxt; nxt = tmp;
    }
}

// ---------------------------------------------------------------------------
// Sequential scan for row 63 (reads rows 61/62 from global, written above).
#define SDEPTH 16
__global__ void scan63(float* __restrict__ dst,
                       const float* __restrict__ src,
                       const float* __restrict__ Wl,
                       const float* __restrict__ bl) {
    const int b = blockIdx.x;
    const int j = threadIdx.x;                         // 0..63, one wave
    float w[9];
#pragma unroll
    for (int k = 0; k < 9; ++k) w[k] = Wl[k];
    const float bias = bl[0];

    const size_t ST = (size_t)D_ * D_;
    const float* s61 = src + (size_t)b * L_ * ST + 61 * 64 + j;
    const float* s62 = src + (size_t)b * L_ * ST + 62 * 64 + j;
    float*       d63 = dst + (size_t)b * L_ * ST + 63 * 64 + j;

    float s = ftanh(bias);                             // t=0: h_{-1}=0
    d63[0] = s;

    float p61[SDEPTH], p62[SDEPTH];
#pragma unroll
    for (int u = 0; u < SDEPTH; ++u) {
        p61[u] = s61[(size_t)u * ST];
        p62[u] = s62[(size_t)u * ST];
    }

    for (int t0 = 1; t0 < 256; t0 += SDEPTH) {
#pragma unroll
        for (int u = 0; u < SDEPTH; ++u) {
            const int t = t0 + u;
            if (t > 255) break;
            const float r61 = p61[u], r62 = p62[u];
            int tp = t + SDEPTH - 1;
            if (tp > 255) tp = 255;
            p61[u] = s61[(size_t)tp * ST];
            p62[u] = s62[(size_t)tp * ST];
            float l1 = dpp_shr1(r61), q1 = dpp_shl1(r61);
            float l2 = dpp_shr1(r62), q2 = dpp_shl1(r62);
            float p = bias;
            p = fmaf(w[0], l1, p); p = fmaf(w[1], r61, p); p = fmaf(w[2], q1, p);
            p = fmaf(w[3], l2, p); p = fmaf(w[4], r62, p); p = fmaf(w[5], q2, p);
            float ls = dpp_shr1(s), rs = dpp_shl1(s);
            float z = fmaf(w[6], ls, fmaf(w[7], s, fmaf(w[8], rs, p)));
            s = ftanh(z);
            d63[(size_t)t * ST] = s;
        }
    }
}

extern "C" void kernel_launch(void* const* d_in, const int* in_sizes, int n_in,
                              void* d_out, int out_size, void* d_ws, size_t ws_size,
                              hipStream_t stream) {
    const float* x    = (const float*)d_in[0];   // (B,L,D,D)
    const float* W    = (const float*)d_in[1];   // (2,1,1,3,3)
    const float* bias = (const float*)d_in[2];   // (2,)
    float* out = (float*)d_out;
    float* h1  = (float*)d_ws;

    for (int l = 0; l < 2; ++l) {
        const float* X  = (l == 0) ? x  : h1;
        float*       H  = (l == 0) ? h1 : out;
        fused_layer<<<B_ * NCH, 512, 0, stream>>>(X, H, W + l * 9, bias + l);
        scan63<<<B_, 64, 0, stream>>>(H, H, W + l * 9, bias + l);
    }
}

// Round 16
// 118.531 us; speedup vs baseline: 1.1174x; 1.0089x over previous
//
#include <hip/hip_runtime.h>
#include <math.h>

#define B_ 16
#define L_ 256
#define D_ 64

#define CHUNK 16                    // 256 blocks = 1/CU
#define WARM  5                     // R13-proven
#define NCH   (L_ / CHUNK)

#define PITCH 64                    // 16 quads/slot; phys quad = dq ^ v(s)
#define NSLOT 127                   // slot 0 = zeros; 1..64 = x rows 0..63; 65..126 = h rows 0..61
#define FBUF  (NSLOT * PITCH)       // 8128 floats
#define LDSZ  (2 * FBUF)            // 63.5 KB

// R16 swizzle: v(s) = (s + (s>>1)) & 7. Parity sequence 0,1,1,0|0,1,1,0 —
// balanced 2+2 over every 4 consecutive slots (write stride 1) AND
// alternating at stride 2 (read stride). The R15 counter (9.5e6 ≈ every
// instr conflicted) indicts 32-lane conflict granularity, where the old
// (s>>1)&7 4-ways all writes.
__device__ __forceinline__ int swz(int s) { return (s + (s >> 1)) & 7; }

// fast tanh via v_exp_f32: overflow/NaN-safe, ~1e-7 rel error (thr 1e-2)
__device__ __forceinline__ float ftanh(float x) {
    float ax = fabsf(x);
    float e  = __builtin_amdgcn_exp2f(-2.8853900818f * ax);   // e^{-2ax}
    float r  = (1.0f - e) * __builtin_amdgcn_rcpf(1.0f + e);
    return copysignf(r, x);
}

// DPP wave shifts with zero boundary fill (bound_ctrl=1).
// Safe ONLY with fully-uniform exec (R11/R15 lesson): used in the
// non-divergent compute region and scan63's single full wave.
__device__ __forceinline__ float dpp_shr1(float x) {
    int r = __builtin_amdgcn_update_dpp(0, __float_as_int(x), 0x138, 0xF, 0xF, true);
    return __int_as_float(r);
}
__device__ __forceinline__ float dpp_shl1(float x) {
    int r = __builtin_amdgcn_update_dpp(0, __float_as_int(x), 0x130, 0xF, 0xF, true);
    return __int_as_float(r);
}

// ---------------------------------------------------------------------------
// fused_layer: rows 0..62 per (b, t-chunk of 16), serial over t. x(t) frame +
// h(t-1) rows 0..61 in one double-buffered XOR-swizzled LDS frame (slot s =
// concat row s-1; data quad dq at phys quad dq^swz(s)). Staging = 2-deep
// register prefetch + swizzled ds_write (R12-proven). Column conv decomposed
// into u0/u1/u2 partial sums; cross-column edge terms via DPP under uniform
// exec (R15-proven). WARM=5: level-k rows exact at tw+k (k<=5).
// Row 63 (truly recurrent) is finished by scan63.
__global__ __launch_bounds__(512, 1) void fused_layer(
        const float* __restrict__ X, float* __restrict__ H,
        const float* __restrict__ Wl, const float* __restrict__ bl) {
    __shared__ float lds[LDSZ];

    const int tid    = threadIdx.x;
    const int b      = blockIdx.x >> 4;
    const int ch     = blockIdx.x & (NCH - 1);
    const int T0     = ch * CHUNK;
    const int tw     = (T0 >= WARM) ? (T0 - WARM) : 0;
    const int tend   = T0 + CHUNK;
    const int btbase = b * L_;

    const int r   = tid >> 3;                          // row 0..63
    const int l8  = tid & 7;
    const int q0  = l8 << 1;                           // own data quads q0, q0+1
    // x-staging offsets (all 512 threads)
    const int sx  = r + 1;
    const int vx  = swz(sx);
    const int xw0 = sx * PITCH + ((q0 ^ vx) << 2);
    const int xw1 = sx * PITCH + (((q0 + 1) ^ vx) << 2);
    // compute mapping: row i; row-63 lanes compute row 62's values (discarded)
    const int  i    = r;
    const int  ic   = (i < 63) ? i : 62;               // clamped read row
    const int  c0   = l8 << 3;
    const int  sh   = 65 + i;                          // h-store slot (i<=61)
    const int  vh   = swz(sh);
    const int  hw0  = sh * PITCH + ((q0 ^ vh) << 2);
    const int  hw1  = sh * PITCH + (((q0 + 1) ^ vh) << 2);
    const bool le0  = (l8 == 0);
    const bool le7  = (l8 == 7);

    // per-ki read offsets (slots 2ic..2ic+2)
    int ro0[3], ro1[3];
#pragma unroll
    for (int ki = 0; ki < 3; ++ki) {
        const int s = 2 * ic + ki;
        const int v = swz(s);
        const int sb = s * PITCH;
        ro0[ki] = sb + ((q0 ^ v) << 2);
        ro1[ki] = sb + (((q0 + 1) ^ v) << 2);
    }

    float w[9];
#pragma unroll
    for (int k = 0; k < 9; ++k) w[k] = Wl[k];
    const float bias = bl[0];
    const float4 z4 = make_float4(0.f, 0.f, 0.f, 0.f);

    for (int k = tid; k < LDSZ / 4; k += 512)
        reinterpret_cast<float4*>(lds)[k] = z4;        // slot 0 + h(-1)=0
    __syncthreads();

    float* cur = lds;
    float* nxt = lds + FBUF;

    // stage x(tw) into cur ((r<<6)+(l8<<3) == tid<<3)
    {
        const float* xg = X + (((size_t)(btbase + tw)) << 12) + (tid << 3);
        *reinterpret_cast<float4*>(cur + xw0) = reinterpret_cast<const float4*>(xg)[0];
        *reinterpret_cast<float4*>(cur + xw1) = reinterpret_cast<const float4*>(xg)[1];
    }
    // register prefetch x(tw+1)
    float4 pa, pb;
    {
        const int t1 = (tw + 1 < L_) ? tw + 1 : L_ - 1;
        const float* xg = X + (((size_t)(btbase + t1)) << 12) + (tid << 3);
        pa = reinterpret_cast<const float4*>(xg)[0];
        pb = reinterpret_cast<const float4*>(xg)[1];
    }
    __syncthreads();

    for (int t = tw; t < tend; ++t) {
        // issue x(t+2) loads — 2 steps deep, off the serial chain
        const int t2 = (t + 2 < L_) ? t + 2 : L_ - 1;
        const float* xg = X + (((size_t)(btbase + t2)) << 12) + (tid << 3);
        const float4 na = reinterpret_cast<const float4*>(xg)[0];
        const float4 nb = reinterpret_cast<const float4*>(xg)[1];

        // ---- non-divergent compute (all 512 threads) ----
        float u0[8], u1[8], u2[8];
#pragma unroll
        for (int k = 0; k < 8; ++k) { u0[k] = 0.f; u1[k] = bias; u2[k] = 0.f; }
#pragma unroll
        for (int ki = 0; ki < 3; ++ki) {
            const float4 o0 = *reinterpret_cast<const float4*>(cur + ro0[ki]);
            const float4 o1 = *reinterpret_cast<const float4*>(cur + ro1[ki]);
            const float g[8] = {o0.x, o0.y, o0.z, o0.w, o1.x, o1.y, o1.z, o1.w};
            const float wa = w[ki*3], wb = w[ki*3+1], wc = w[ki*3+2];
#pragma unroll
            for (int k = 0; k < 8; ++k) {
                u0[k] = fmaf(wa, g[k], u0[k]);
                u1[k] = fmaf(wb, g[k], u1[k]);
                u2[k] = fmaf(wc, g[k], u2[k]);
            }
        }
        // cross-lane edges (uniform exec): left lane's u0[7], right lane's u2[0]
        const float eLr = dpp_shr1(u0[7]);
        const float eRr = dpp_shl1(u2[0]);
        const float eL  = le0 ? 0.f : eLr;             // col c0-1 term
        const float eR  = le7 ? 0.f : eRr;             // col c0+8 term

        float o[8];
        o[0] = ftanh(eL + u1[0] + u2[1]);
#pragma unroll
        for (int k = 1; k < 7; ++k)
            o[k] = ftanh(u0[k-1] + u1[k] + u2[k+1]);
        o[7] = ftanh(u0[6] + u1[7] + eR);

        // ---- predicated stores (divergence after all DPP) ----
        if (i < 63 && t >= T0) {
            float* gd = H + (((size_t)(btbase + t)) << 12) + (i << 6) + c0;
            *reinterpret_cast<float4*>(gd)     = make_float4(o[0],o[1],o[2],o[3]);
            *reinterpret_cast<float4*>(gd + 4) = make_float4(o[4],o[5],o[6],o[7]);
        }
        if (i <= 61) {                                 // h row for next step
            *reinterpret_cast<float4*>(nxt + hw0) = make_float4(o[0],o[1],o[2],o[3]);
            *reinterpret_cast<float4*>(nxt + hw1) = make_float4(o[4],o[5],o[6],o[7]);
        }
        {   // commit x(t+1) into nxt
            *reinterpret_cast<float4*>(nxt + xw0) = pa;
            *reinterpret_cast<float4*>(nxt + xw1) = pb;
        }
        __syncthreads();
        pa = na; pb = nb;
        float* tmp = cur; cur = nxt; nxt = tmp;
    }
}

// ---------------------------------------------------------------------------
// Sequential scan for row 63 (reads rows 61/62 from global, written above).
#define SDEPTH 16
__global__ void scan63(float* __restrict__ dst,
                       const float* __restrict__ src,
                       const float* __restrict__ Wl,
                       const float* __restrict__ bl) {
    const int b = blockIdx.x;
    const int j = threadIdx.x;                         // 0..63, one wave
    float w[9];
#pragma unroll
    for (int k = 0; k < 9; ++k) w[k] = Wl[k];
    const float bias = bl[0];

    const size_t ST = (size_t)D_ * D_;
    const float* s61 = src + (size_t)b * L_ * ST + 61 * 64 + j;
    const float* s62 = src + (size_t)b * L_ * ST + 62 * 64 + j;
    float*       d63 = dst + (size_t)b * L_ * ST + 63 * 64 + j;

    float s = ftanh(bias);                             // t=0: h_{-1}=0
    d63[0] = s;

    float p61[SDEPTH], p62[SDEPTH];
#pragma unroll
    for (int u = 0; u < SDEPTH; ++u) {
        p61[u] = s61[(size_t)u * ST];
        p62[u] = s62[(size_t)u * ST];
    }

    for (int t0 = 1; t0 < 256; t0 += SDEPTH) {
#pragma unroll
        for (int u = 0; u < SDEPTH; ++u) {
            const int t = t0 + u;
            if (t > 255) break;
            const float r61 = p61[u], r62 = p62[u];
            int tp = t + SDEPTH - 1;
            if (tp > 255) tp = 255;
            p61[u] = s61[(size_t)tp * ST];
            p62[u] = s62[(size_t)tp * ST];
            float l1 = dpp_shr1(r61), q1 = dpp_shl1(r61);
            float l2 = dpp_shr1(r62), q2 = dpp_shl1(r62);
            float p = bias;
            p = fmaf(w[0], l1, p); p = fmaf(w[1], r61, p); p = fmaf(w[2], q1, p);
            p = fmaf(w[3], l2, p); p = fmaf(w[4], r62, p); p = fmaf(w[5], q2, p);
            float ls = dpp_shr1(s), rs = dpp_shl1(s);
            float z = fmaf(w[6], ls, fmaf(w[7], s, fmaf(w[8], rs, p)));
            s = ftanh(z);
            d63[(size_t)t * ST] = s;
        }
    }
}

extern "C" void kernel_launch(void* const* d_in, const int* in_sizes, int n_in,
                              void* d_out, int out_size, void* d_ws, size_t ws_size,
                              hipStream_t stream) {
    const float* x    = (const float*)d_in[0];   // (B,L,D,D)
    const float* W    = (const float*)d_in[1];   // (2,1,1,3,3)
    const float* bias = (const float*)d_in[2];   // (2,)
    float* out = (float*)d_out;
    float* h1  = (float*)d_ws;

    for (int l = 0; l < 2; ++l) {
        const float* X  = (l == 0) ? x  : h1;
        float*       H  = (l == 0) ? h1 : out;
        fused_layer<<<B_ * NCH, 512, 0, stream>>>(X, H, W + l * 9, bias + l);
        scan63<<<B_, 64, 0, stream>>>(H, H, W + l * 9, bias + l);
    }
}